// Round 1
// baseline (1071.492 us; speedup 1.0000x reference)
//
#include <hip/hip_runtime.h>

#define N_NODES 50000
#define N_EDGES 800000
#define D_IN    256
#define D_HID   512

// ---------------- workspace layout (all 256B aligned) ----------------
constexpr size_t OFF_FLAG  = 0;                       // int flag (1 => edge_index is int64)
constexpr size_t OFF_EDGES = 256;                     // 2*N_EDGES ints: src[0..E), dst[E..2E)
constexpr size_t OFF_CNT   = OFF_EDGES + 6400000;     // N_NODES ints
constexpr size_t OFF_OFFS  = OFF_CNT   + 200192;      // N_NODES+1 ints
constexpr size_t OFF_CUR   = OFF_OFFS  + 200448;      // N_NODES ints
constexpr size_t OFF_SORT  = OFF_CUR   + 200192;      // N_EDGES ints (src sorted by dst)
constexpr size_t OFF_MEAN  = OFF_SORT  + 3200000;     // N_NODES * D_IN f32

// ---------------- dtype detection: int64 vs int32 edge_index ----------------
__global__ void detect_kernel(const unsigned int* __restrict__ ei, int* __restrict__ flag) {
    __shared__ int any;
    if (threadIdx.x == 0) any = 0;
    __syncthreads();
    int local = 0;
    // If int64: odd u32 words are high words of values in [0, 50000) -> all 0.
    // If int32: odd words are edge indices -> essentially surely nonzero somewhere.
    for (int i = threadIdx.x; i < 4096; i += blockDim.x)
        local |= (ei[2 * i + 1] != 0u);
    if (local) any = 1;
    __syncthreads();
    if (threadIdx.x == 0) *flag = any ? 0 : 1;   // 1 => int64
}

__global__ void convert_kernel(const void* __restrict__ ei, const int* __restrict__ flag,
                               int* __restrict__ edges32) {
    int i = blockIdx.x * blockDim.x + threadIdx.x;
    if (i >= 2 * N_EDGES) return;
    int v;
    if (*flag) v = (int)((const long long*)ei)[i];
    else       v = ((const int*)ei)[i];
    edges32[i] = v;
}

// ---------------- CSR build ----------------
__global__ void hist_kernel(const int* __restrict__ dst, int* __restrict__ cnt) {
    int e = blockIdx.x * blockDim.x + threadIdx.x;
    if (e < N_EDGES) atomicAdd(&cnt[dst[e]], 1);
}

// single-block exclusive scan over N_NODES counts -> offs[0..N_NODES]
__global__ void scan_kernel(const int* __restrict__ cnt, int* __restrict__ offs) {
    __shared__ int wsum[4];
    __shared__ int s_carry;
    const int tid = threadIdx.x, lane = tid & 63, wid = tid >> 6;
    if (tid == 0) s_carry = 0;
    __syncthreads();
    for (int base = 0; base < N_NODES; base += 256) {
        int idx = base + tid;
        int v = (idx < N_NODES) ? cnt[idx] : 0;
        int x = v;
        #pragma unroll
        for (int d = 1; d < 64; d <<= 1) {
            int y = __shfl_up(x, d);
            if (lane >= d) x += y;
        }
        if (lane == 63) wsum[wid] = x;
        __syncthreads();
        int wpre = 0;
        for (int w = 0; w < wid; ++w) wpre += wsum[w];
        int incl = x + wpre;                 // inclusive scan within chunk
        int carry = s_carry;
        if (idx < N_NODES) offs[idx] = carry + incl - v;  // exclusive
        __syncthreads();
        if (tid == 255) s_carry = carry + incl;           // chunk total
        __syncthreads();
    }
    if (threadIdx.x == 0) offs[N_NODES] = s_carry;
}

__global__ void scatter_kernel(const int* __restrict__ src, const int* __restrict__ dst,
                               const int* __restrict__ offs, int* __restrict__ cursor,
                               int* __restrict__ sorted_src) {
    int e = blockIdx.x * blockDim.x + threadIdx.x;
    if (e >= N_EDGES) return;
    int d = dst[e];
    int p = offs[d] + atomicAdd(&cursor[d], 1);
    sorted_src[p] = src[e];
}

// ---------------- mean aggregation: one wave per node ----------------
__global__ void agg_kernel(const float* __restrict__ x, const int* __restrict__ offs,
                           const int* __restrict__ sorted_src, float* __restrict__ mean) {
    int gw = (blockIdx.x * blockDim.x + threadIdx.x) >> 6;   // global wave id = node
    int lane = threadIdx.x & 63;
    if (gw >= N_NODES) return;
    int beg = offs[gw], end = offs[gw + 1];
    float4 acc = make_float4(0.f, 0.f, 0.f, 0.f);
    for (int k = beg; k < end; ++k) {
        int s = sorted_src[k];
        const float4 v = *reinterpret_cast<const float4*>(x + (size_t)s * D_IN + lane * 4);
        acc.x += v.x; acc.y += v.y; acc.z += v.z; acc.w += v.w;
    }
    int c = end - beg;
    float inv = (c > 0) ? (1.0f / (float)c) : 0.0f;
    acc.x *= inv; acc.y *= inv; acc.z *= inv; acc.w *= inv;
    *reinterpret_cast<float4*>(mean + (size_t)gw * D_IN + lane * 4) = acc;
}

// ---------------- fused GEMM: out = [mean|x] @ [W_l;W_r] + b ----------------
#define BM 64
#define BN 64
#define BK 16

__global__ __launch_bounds__(256) void gemm_kernel(
        const float* __restrict__ mean, const float* __restrict__ x,
        const float* __restrict__ Wl, const float* __restrict__ Wr,
        const float* __restrict__ bias, float* __restrict__ out) {
    __shared__ float As[BM][BK + 1];   // +1 pad: kills bank conflicts on As[m][kk]
    __shared__ float Bs[BK][BN];       // float4 reads span all banks

    const int tid = threadIdx.x;
    const int mtile = blockIdx.x / (D_HID / BN);
    const int ntile = blockIdx.x % (D_HID / BN);
    const int row0 = mtile * BM, col0 = ntile * BN;
    const int tx = tid & 15, ty = tid >> 4;    // 16x16 thread grid, 4x4 per thread

    float acc[4][4] = {};

    for (int k0 = 0; k0 < 2 * D_IN; k0 += BK) {
        #pragma unroll
        for (int i = 0; i < 4; ++i) {          // A tile: 64 rows x 16 k
            int idx = i * 256 + tid;
            int r = idx >> 4, kk = idx & 15;
            int grow = row0 + r, gk = k0 + kk;
            float v = 0.f;
            if (grow < N_NODES)
                v = (gk < D_IN) ? mean[(size_t)grow * D_IN + gk]
                                : x[(size_t)grow * D_IN + (gk - D_IN)];
            As[r][kk] = v;
        }
        #pragma unroll
        for (int i = 0; i < 4; ++i) {          // B tile: 16 k x 64 n
            int idx = i * 256 + tid;
            int kk = idx >> 6, n = idx & 63;
            int gk = k0 + kk;
            float v = (gk < D_IN) ? Wl[(size_t)gk * D_HID + col0 + n]
                                  : Wr[(size_t)(gk - D_IN) * D_HID + col0 + n];
            Bs[kk][n] = v;
        }
        __syncthreads();
        #pragma unroll
        for (int kk = 0; kk < BK; ++kk) {
            float a0 = As[ty * 4 + 0][kk];
            float a1 = As[ty * 4 + 1][kk];
            float a2 = As[ty * 4 + 2][kk];
            float a3 = As[ty * 4 + 3][kk];
            float4 b4 = *reinterpret_cast<const float4*>(&Bs[kk][tx * 4]);
            acc[0][0] += a0 * b4.x; acc[0][1] += a0 * b4.y; acc[0][2] += a0 * b4.z; acc[0][3] += a0 * b4.w;
            acc[1][0] += a1 * b4.x; acc[1][1] += a1 * b4.y; acc[1][2] += a1 * b4.z; acc[1][3] += a1 * b4.w;
            acc[2][0] += a2 * b4.x; acc[2][1] += a2 * b4.y; acc[2][2] += a2 * b4.z; acc[2][3] += a2 * b4.w;
            acc[3][0] += a3 * b4.x; acc[3][1] += a3 * b4.y; acc[3][2] += a3 * b4.z; acc[3][3] += a3 * b4.w;
        }
        __syncthreads();
    }

    float4 bv = *reinterpret_cast<const float4*>(&bias[col0 + tx * 4]);
    #pragma unroll
    for (int i = 0; i < 4; ++i) {
        int grow = row0 + ty * 4 + i;
        if (grow < N_NODES) {
            float4 o;
            o.x = acc[i][0] + bv.x; o.y = acc[i][1] + bv.y;
            o.z = acc[i][2] + bv.z; o.w = acc[i][3] + bv.w;
            *reinterpret_cast<float4*>(&out[(size_t)grow * D_HID + col0 + tx * 4]) = o;
        }
    }
}

// ---------------- launcher ----------------
extern "C" void kernel_launch(void* const* d_in, const int* in_sizes, int n_in,
                              void* d_out, int out_size, void* d_ws, size_t ws_size,
                              hipStream_t stream) {
    const float* x    = (const float*)d_in[0];
    const void*  ei   = d_in[1];
    const float* Wl   = (const float*)d_in[2];
    const float* Wr   = (const float*)d_in[3];
    const float* bias = (const float*)d_in[4];
    float* out = (float*)d_out;

    char* ws = (char*)d_ws;
    int*   flag       = (int*)(ws + OFF_FLAG);
    int*   edges32    = (int*)(ws + OFF_EDGES);
    int*   src32      = edges32;
    int*   dst32      = edges32 + N_EDGES;
    int*   cnt        = (int*)(ws + OFF_CNT);
    int*   offs       = (int*)(ws + OFF_OFFS);
    int*   cursor     = (int*)(ws + OFF_CUR);
    int*   sorted_src = (int*)(ws + OFF_SORT);
    float* mean       = (float*)(ws + OFF_MEAN);

    // zero counters (ws is poisoned 0xAA before every timed launch)
    hipMemsetAsync(cnt, 0, N_NODES * sizeof(int), stream);
    hipMemsetAsync(cursor, 0, N_NODES * sizeof(int), stream);

    detect_kernel<<<1, 256, 0, stream>>>((const unsigned int*)ei, flag);
    convert_kernel<<<(2 * N_EDGES + 255) / 256, 256, 0, stream>>>(ei, flag, edges32);
    hist_kernel<<<(N_EDGES + 255) / 256, 256, 0, stream>>>(dst32, cnt);
    scan_kernel<<<1, 256, 0, stream>>>(cnt, offs);
    scatter_kernel<<<(N_EDGES + 255) / 256, 256, 0, stream>>>(src32, dst32, offs, cursor, sorted_src);
    agg_kernel<<<(N_NODES * 64 + 255) / 256, 256, 0, stream>>>(x, offs, sorted_src, mean);

    const int mtiles = (N_NODES + BM - 1) / BM;      // 782
    const int ntiles = D_HID / BN;                   // 8
    gemm_kernel<<<mtiles * ntiles, 256, 0, stream>>>(mean, x, Wl, Wr, bias, out);
}

// Round 3
// 572.435 us; speedup vs baseline: 1.8718x; 1.8718x over previous
//
#include <hip/hip_runtime.h>

#define N_NODES 50000
#define N_EDGES 800000
#define D_IN    256
#define D_HID   512

typedef __attribute__((ext_vector_type(8))) short bf16x8;
typedef __attribute__((ext_vector_type(4))) float f32x4;

// ---------------- workspace layout (peak 61.4 MB, proven in R1) ----------------
constexpr size_t OFF_FLAG  = 0;                       // int flag (1 => edge_index is int64)
constexpr size_t OFF_EDGES = 256;                     // 2*N_EDGES ints: src[0..E), dst[E..2E)
constexpr size_t OFF_BHT   = OFF_EDGES;               // 512*512 bf16 — reuses edges32 AFTER scatter
constexpr size_t OFF_BLT   = OFF_BHT   + 524288;
constexpr size_t OFF_CNT   = OFF_EDGES + 6400000;     // N_NODES ints
constexpr size_t OFF_OFFS  = OFF_CNT   + 200192;      // N_NODES+1 ints
constexpr size_t OFF_CUR   = OFF_OFFS  + 200448;      // N_NODES ints
constexpr size_t OFF_SORT  = OFF_CUR   + 200192;      // N_EDGES ints (src sorted by dst)
constexpr size_t OFF_MEAN  = OFF_SORT  + 3200000;     // N_NODES * D_IN f32 (ends at 61.4MB)

// ---------------- helpers ----------------
__device__ inline unsigned bf16_rne_bits(float f) {   // returns bf16 in low 16
    unsigned u = __float_as_uint(f);
    return (u + 0x7fffu + ((u >> 16) & 1u)) >> 16;
}

// ---------------- dtype detection: int64 vs int32 edge_index ----------------
__global__ void detect_kernel(const unsigned int* __restrict__ ei, int* __restrict__ flag) {
    __shared__ int any;
    if (threadIdx.x == 0) any = 0;
    __syncthreads();
    int local = 0;
    for (int i = threadIdx.x; i < 4096; i += blockDim.x)
        local |= (ei[2 * i + 1] != 0u);
    if (local) any = 1;
    __syncthreads();
    if (threadIdx.x == 0) *flag = any ? 0 : 1;   // 1 => int64
}

__global__ void convert_kernel(const void* __restrict__ ei, const int* __restrict__ flag,
                               int* __restrict__ edges32) {
    int i = blockIdx.x * blockDim.x + threadIdx.x;
    if (i >= 2 * N_EDGES) return;
    int v;
    if (*flag) v = (int)((const long long*)ei)[i];
    else       v = ((const int*)ei)[i];
    edges32[i] = v;
}

// ---------------- CSR build ----------------
__global__ void hist_kernel(const int* __restrict__ dst, int* __restrict__ cnt) {
    int e = blockIdx.x * blockDim.x + threadIdx.x;
    if (e < N_EDGES) atomicAdd(&cnt[dst[e]], 1);
}

__global__ void scan_kernel(const int* __restrict__ cnt, int* __restrict__ offs) {
    __shared__ int wsum[4];
    __shared__ int s_carry;
    const int tid = threadIdx.x, lane = tid & 63, wid = tid >> 6;
    if (tid == 0) s_carry = 0;
    __syncthreads();
    for (int base = 0; base < N_NODES; base += 256) {
        int idx = base + tid;
        int v = (idx < N_NODES) ? cnt[idx] : 0;
        int x = v;
        #pragma unroll
        for (int d = 1; d < 64; d <<= 1) {
            int y = __shfl_up(x, d);
            if (lane >= d) x += y;
        }
        if (lane == 63) wsum[wid] = x;
        __syncthreads();
        int wpre = 0;
        for (int w = 0; w < wid; ++w) wpre += wsum[w];
        int incl = x + wpre;
        int carry = s_carry;
        if (idx < N_NODES) offs[idx] = carry + incl - v;
        __syncthreads();
        if (tid == 255) s_carry = carry + incl;
        __syncthreads();
    }
    if (threadIdx.x == 0) offs[N_NODES] = s_carry;
}

__global__ void scatter_kernel(const int* __restrict__ src, const int* __restrict__ dst,
                               const int* __restrict__ offs, int* __restrict__ cursor,
                               int* __restrict__ sorted_src) {
    int e = blockIdx.x * blockDim.x + threadIdx.x;
    if (e >= N_EDGES) return;
    int d = dst[e];
    int p = offs[d] + atomicAdd(&cursor[d], 1);
    sorted_src[p] = src[e];
}

// ---------------- mean aggregation: one wave per node ----------------
__global__ void agg_kernel(const float* __restrict__ x, const int* __restrict__ offs,
                           const int* __restrict__ sorted_src, float* __restrict__ mean) {
    int gw = (blockIdx.x * blockDim.x + threadIdx.x) >> 6;
    int lane = threadIdx.x & 63;
    if (gw >= N_NODES) return;
    int beg = __builtin_amdgcn_readfirstlane(offs[gw]);
    int end = __builtin_amdgcn_readfirstlane(offs[gw + 1]);
    float ax0=0.f, ay0=0.f, az0=0.f, aw0=0.f;
    float ax1=0.f, ay1=0.f, az1=0.f, aw1=0.f;
    int k = beg;
    for (; k + 2 <= end; k += 2) {
        int s0 = __builtin_amdgcn_readfirstlane(sorted_src[k]);
        int s1 = __builtin_amdgcn_readfirstlane(sorted_src[k + 1]);
        float4 v0 = *reinterpret_cast<const float4*>(x + (size_t)s0 * D_IN + lane * 4);
        float4 v1 = *reinterpret_cast<const float4*>(x + (size_t)s1 * D_IN + lane * 4);
        ax0 += v0.x; ay0 += v0.y; az0 += v0.z; aw0 += v0.w;
        ax1 += v1.x; ay1 += v1.y; az1 += v1.z; aw1 += v1.w;
    }
    if (k < end) {
        int s0 = __builtin_amdgcn_readfirstlane(sorted_src[k]);
        float4 v0 = *reinterpret_cast<const float4*>(x + (size_t)s0 * D_IN + lane * 4);
        ax0 += v0.x; ay0 += v0.y; az0 += v0.z; aw0 += v0.w;
    }
    int c = end - beg;
    float inv = (c > 0) ? (1.0f / (float)c) : 0.0f;
    float4 o;
    o.x = (ax0 + ax1) * inv; o.y = (ay0 + ay1) * inv;
    o.z = (az0 + az1) * inv; o.w = (aw0 + aw1) * inv;
    *reinterpret_cast<float4*>(mean + (size_t)gw * D_IN + lane * 4) = o;
}

// ---------------- W prep: B' = [Wl;Wr] -> transposed bf16 hi/lo ----------------
// BhT[n][k], BlT[n][k], n,k in [0,512)
__global__ void prepw_kernel(const float* __restrict__ Wl, const float* __restrict__ Wr,
                             unsigned short* __restrict__ BhT, unsigned short* __restrict__ BlT) {
    int idx = blockIdx.x * blockDim.x + threadIdx.x;   // 262144 total
    if (idx >= 512 * 512) return;
    int n = idx >> 9, k = idx & 511;
    float v = (k < 256) ? Wl[(size_t)k * D_HID + n] : Wr[(size_t)(k - 256) * D_HID + n];
    unsigned u = __float_as_uint(v);
    unsigned hi_aligned = (u + 0x7fffu + ((u >> 16) & 1u)) & 0xffff0000u;
    float hf = __uint_as_float(hi_aligned);
    float lo = v - hf;
    BhT[idx] = (unsigned short)(hi_aligned >> 16);
    BlT[idx] = (unsigned short)bf16_rne_bits(lo);
}

// ---------------- split-bf16 MFMA GEMM ----------------
// C[M,512] = A[M,512] @ B[512,512] + bias, A = [mean | x] fp32, done as
// Ah@Bh + Al@Bh + Ah@Bl with bf16 hi/lo splits. Tile 128x128, K-step 32.
#define GBM 128
#define GBN 128
#define GBK 32

// 16B slots; ((r>>1)&3)^g spreads 8 consecutive rows over all 8 bank-groups
// (2-way min aliasing for wave64 b128 — free per m136). Bijective in g per row.
__device__ inline int lds_slot(int r, int g) { return r * 4 + (((r >> 1) & 3) ^ g); }

__global__ __launch_bounds__(256, 2) void gemm_mfma(
        const float* __restrict__ mean, const float* __restrict__ x,
        const unsigned short* __restrict__ BhT, const unsigned short* __restrict__ BlT,
        const float* __restrict__ bias, float* __restrict__ out) {
    __shared__ __align__(16) unsigned short Ah_s[GBM * GBK];  // 8KB each
    __shared__ __align__(16) unsigned short Al_s[GBM * GBK];
    __shared__ __align__(16) unsigned short Bh_s[GBN * GBK];  // [n][k] layout
    __shared__ __align__(16) unsigned short Bl_s[GBN * GBK];

    const int tid  = threadIdx.x;
    const int lane = tid & 63, wave = tid >> 6;
    const int wr = wave >> 1, wc = wave & 1;          // 2x2 waves of 64x64
    const int mtile = blockIdx.x >> 2;                // ntile fastest for A L2 reuse
    const int ntile = blockIdx.x & 3;
    const int row0 = mtile * GBM, col0 = ntile * GBN;

    // A staging map: thread -> (row, 16-col half)
    const int ar  = tid >> 1;
    const int ach = tid & 1;
    const int agrow = row0 + ar;
    const bool aok = (agrow < N_NODES);

    const int fr = lane & 15, fg = lane >> 4;         // fragment lane decomposition

    f32x4 acc[4][4];
    #pragma unroll
    for (int i = 0; i < 4; ++i)
        #pragma unroll
        for (int j = 0; j < 4; ++j) acc[i][j] = (f32x4)0.f;

    for (int k0 = 0; k0 < 512; k0 += GBK) {
        // ---- stage A: load 16 fp32, split to hi/lo bf16, swizzled ds_write
        {
            const int k0c = k0 + ach * 16;
            float f[16];
            if (aok) {
                const float* asrc = (k0c < 256)
                    ? (mean + (size_t)agrow * D_IN + k0c)
                    : (x    + (size_t)agrow * D_IN + (k0c - 256));
                float4 v0 = *reinterpret_cast<const float4*>(asrc + 0);
                float4 v1 = *reinterpret_cast<const float4*>(asrc + 4);
                float4 v2 = *reinterpret_cast<const float4*>(asrc + 8);
                float4 v3 = *reinterpret_cast<const float4*>(asrc + 12);
                f[0]=v0.x; f[1]=v0.y; f[2]=v0.z; f[3]=v0.w;
                f[4]=v1.x; f[5]=v1.y; f[6]=v1.z; f[7]=v1.w;
                f[8]=v2.x; f[9]=v2.y; f[10]=v2.z; f[11]=v2.w;
                f[12]=v3.x; f[13]=v3.y; f[14]=v3.z; f[15]=v3.w;
            } else {
                #pragma unroll
                for (int e = 0; e < 16; ++e) f[e] = 0.f;
            }
            unsigned h[16], l[16];
            #pragma unroll
            for (int e = 0; e < 16; ++e) {
                unsigned u = __float_as_uint(f[e]);
                unsigned ha = (u + 0x7fffu + ((u >> 16) & 1u)) & 0xffff0000u;
                h[e] = ha;
                float lo = f[e] - __uint_as_float(ha);
                l[e] = bf16_rne_bits(lo);
            }
            uint4 hv0, hv1, lv0, lv1;
            hv0.x = (h[1] & 0xffff0000u)  | (h[0] >> 16);
            hv0.y = (h[3] & 0xffff0000u)  | (h[2] >> 16);
            hv0.z = (h[5] & 0xffff0000u)  | (h[4] >> 16);
            hv0.w = (h[7] & 0xffff0000u)  | (h[6] >> 16);
            hv1.x = (h[9] & 0xffff0000u)  | (h[8] >> 16);
            hv1.y = (h[11] & 0xffff0000u) | (h[10] >> 16);
            hv1.z = (h[13] & 0xffff0000u) | (h[12] >> 16);
            hv1.w = (h[15] & 0xffff0000u) | (h[14] >> 16);
            lv0.x = (l[1] << 16) | l[0];
            lv0.y = (l[3] << 16) | l[2];
            lv0.z = (l[5] << 16) | l[4];
            lv0.w = (l[7] << 16) | l[6];
            lv1.x = (l[9] << 16) | l[8];
            lv1.y = (l[11] << 16) | l[10];
            lv1.z = (l[13] << 16) | l[12];
            lv1.w = (l[15] << 16) | l[14];
            const int g0 = 2 * ach, g1 = 2 * ach + 1;
            *reinterpret_cast<uint4*>(&Ah_s[lds_slot(ar, g0) * 8]) = hv0;
            *reinterpret_cast<uint4*>(&Ah_s[lds_slot(ar, g1) * 8]) = hv1;
            *reinterpret_cast<uint4*>(&Al_s[lds_slot(ar, g0) * 8]) = lv0;
            *reinterpret_cast<uint4*>(&Al_s[lds_slot(ar, g1) * 8]) = lv1;
        }
        // ---- stage B: copy bf16 tiles (hi & lo), swizzled
        #pragma unroll
        for (int i = 0; i < 2; ++i) {
            int s = i * 256 + tid;
            int br = s >> 2, bg = s & 3;
            size_t goff = (size_t)(col0 + br) * 512 + k0 + bg * 8;
            uint4 hb = *reinterpret_cast<const uint4*>(BhT + goff);
            uint4 lb = *reinterpret_cast<const uint4*>(BlT + goff);
            *reinterpret_cast<uint4*>(&Bh_s[lds_slot(br, bg) * 8]) = hb;
            *reinterpret_cast<uint4*>(&Bl_s[lds_slot(br, bg) * 8]) = lb;
        }
        __syncthreads();

        // ---- fragments + 48 MFMA (3 split-products x 16 tiles)
        bf16x8 ah[4], al[4], bh[4], bl[4];
        #pragma unroll
        for (int m = 0; m < 4; ++m) {
            int r = wr * 64 + m * 16 + fr;
            ah[m] = *reinterpret_cast<const bf16x8*>(&Ah_s[lds_slot(r, fg) * 8]);
            al[m] = *reinterpret_cast<const bf16x8*>(&Al_s[lds_slot(r, fg) * 8]);
        }
        #pragma unroll
        for (int n = 0; n < 4; ++n) {
            int r = wc * 64 + n * 16 + fr;
            bh[n] = *reinterpret_cast<const bf16x8*>(&Bh_s[lds_slot(r, fg) * 8]);
            bl[n] = *reinterpret_cast<const bf16x8*>(&Bl_s[lds_slot(r, fg) * 8]);
        }
        #pragma unroll
        for (int m = 0; m < 4; ++m)
            #pragma unroll
            for (int n = 0; n < 4; ++n) {
                acc[m][n] = __builtin_amdgcn_mfma_f32_16x16x32_bf16(ah[m], bh[n], acc[m][n], 0, 0, 0);
                acc[m][n] = __builtin_amdgcn_mfma_f32_16x16x32_bf16(al[m], bh[n], acc[m][n], 0, 0, 0);
                acc[m][n] = __builtin_amdgcn_mfma_f32_16x16x32_bf16(ah[m], bl[n], acc[m][n], 0, 0, 0);
            }
        __syncthreads();
    }

    // ---- epilogue: C/D layout col=lane&15, row=(lane>>4)*4+v  [m89-verified]
    float bv[4];
    #pragma unroll
    for (int n = 0; n < 4; ++n) bv[n] = bias[col0 + wc * 64 + n * 16 + fr];
    #pragma unroll
    for (int m = 0; m < 4; ++m) {
        #pragma unroll
        for (int v = 0; v < 4; ++v) {
            int grow = row0 + wr * 64 + m * 16 + fg * 4 + v;
            if (grow < N_NODES) {
                size_t base = (size_t)grow * D_HID + col0 + wc * 64 + fr;
                #pragma unroll
                for (int n = 0; n < 4; ++n)
                    out[base + n * 16] = acc[m][n][v] + bv[n];
            }
        }
    }
}

// ---------------- launcher ----------------
extern "C" void kernel_launch(void* const* d_in, const int* in_sizes, int n_in,
                              void* d_out, int out_size, void* d_ws, size_t ws_size,
                              hipStream_t stream) {
    const float* x    = (const float*)d_in[0];
    const void*  ei   = d_in[1];
    const float* Wl   = (const float*)d_in[2];
    const float* Wr   = (const float*)d_in[3];
    const float* bias = (const float*)d_in[4];
    float* out = (float*)d_out;

    char* ws = (char*)d_ws;
    int*   flag       = (int*)(ws + OFF_FLAG);
    int*   edges32    = (int*)(ws + OFF_EDGES);
    int*   src32      = edges32;
    int*   dst32      = edges32 + N_EDGES;
    int*   cnt        = (int*)(ws + OFF_CNT);
    int*   offs       = (int*)(ws + OFF_OFFS);
    int*   cursor     = (int*)(ws + OFF_CUR);
    int*   sorted_src = (int*)(ws + OFF_SORT);
    float* mean       = (float*)(ws + OFF_MEAN);
    unsigned short* BhT = (unsigned short*)(ws + OFF_BHT);   // aliases edges32 (dead after scatter)
    unsigned short* BlT = (unsigned short*)(ws + OFF_BLT);

    hipMemsetAsync(cnt, 0, N_NODES * sizeof(int), stream);
    hipMemsetAsync(cursor, 0, N_NODES * sizeof(int), stream);

    detect_kernel<<<1, 256, 0, stream>>>((const unsigned int*)ei, flag);
    convert_kernel<<<(2 * N_EDGES + 255) / 256, 256, 0, stream>>>(ei, flag, edges32);
    hist_kernel<<<(N_EDGES + 255) / 256, 256, 0, stream>>>(dst32, cnt);
    scan_kernel<<<1, 256, 0, stream>>>(cnt, offs);
    scatter_kernel<<<(N_EDGES + 255) / 256, 256, 0, stream>>>(src32, dst32, offs, cursor, sorted_src);
    // edges32 region is dead from here on -> prepw reuses it for BhT/BlT
    prepw_kernel<<<(512 * 512 + 255) / 256, 256, 0, stream>>>(Wl, Wr, BhT, BlT);
    agg_kernel<<<(N_NODES * 64 + 255) / 256, 256, 0, stream>>>(x, offs, sorted_src, mean);

    const int mtiles = (N_NODES + GBM - 1) / GBM;   // 391
    gemm_mfma<<<mtiles * 4, 256, 0, stream>>>(mean, x, BhT, BlT, bias, out);
}

// Round 4
// 435.877 us; speedup vs baseline: 2.4582x; 1.3133x over previous
//
#include <hip/hip_runtime.h>

#define N_NODES 50000
#define N_EDGES 800000
#define D_IN    256
#define D_HID   512
#define NBLK    196            // ceil(N_NODES/256)

typedef __attribute__((ext_vector_type(8))) short bf16x8;
typedef __attribute__((ext_vector_type(4))) float f32x4;

// ---------------- workspace layout (peak 61,401,088 B — proven in R1/R3) ----------------
constexpr size_t OFF_FLAG  = 0;                       // int flag (1 => edge_index is int64)
constexpr size_t OFF_EDGES = 256;                     // 2*N_EDGES ints: src[0..E), dst[E..2E)
constexpr size_t OFF_BHT   = OFF_EDGES;               // 512*512 bf16 — reuses edges32 AFTER scatter
constexpr size_t OFF_BLT   = OFF_BHT   + 524288;
constexpr size_t OFF_CNT   = OFF_EDGES + 6400000;     // N_NODES ints
constexpr size_t OFF_OFFS  = OFF_CNT   + 200192;      // N_NODES+1 ints
constexpr size_t OFF_CUR   = OFF_OFFS  + 200448;      // N_NODES ints (also hosts bsum/boff pre-scatter)
constexpr size_t OFF_BSUM  = OFF_CUR;                 // NBLK ints   (dead before cursor memset)
constexpr size_t OFF_BOFF  = OFF_CUR   + 1024;        // NBLK ints
constexpr size_t OFF_SORT  = OFF_CUR   + 200192;      // N_EDGES ints (src sorted by dst)
constexpr size_t OFF_MEAN  = OFF_SORT  + 3200000;     // N_NODES * D_IN f32 (ends at 61.4MB)

// ---------------- helpers ----------------
__device__ inline unsigned bf16_rne_bits(float f) {   // returns bf16 in low 16
    unsigned u = __float_as_uint(f);
    return (u + 0x7fffu + ((u >> 16) & 1u)) >> 16;
}

// ---------------- dtype detection: int64 vs int32 edge_index ----------------
__global__ void detect_kernel(const unsigned int* __restrict__ ei, int* __restrict__ flag) {
    __shared__ int any;
    if (threadIdx.x == 0) any = 0;
    __syncthreads();
    int local = 0;
    for (int i = threadIdx.x; i < 4096; i += blockDim.x)
        local |= (ei[2 * i + 1] != 0u);
    if (local) any = 1;
    __syncthreads();
    if (threadIdx.x == 0) *flag = any ? 0 : 1;   // 1 => int64
}

// convert + fused dst-histogram (cnt must be zeroed before)
__global__ void convert_hist_kernel(const void* __restrict__ ei, const int* __restrict__ flag,
                                    int* __restrict__ edges32, int* __restrict__ cnt) {
    int i = blockIdx.x * blockDim.x + threadIdx.x;
    if (i >= 2 * N_EDGES) return;
    int v;
    if (*flag) v = (int)((const long long*)ei)[i];
    else       v = ((const int*)ei)[i];
    edges32[i] = v;
    if (i >= N_EDGES) atomicAdd(&cnt[v], 1);      // dst half
}

// ---------------- hierarchical scan: offs = exclusive_scan(cnt) ----------------
__global__ void scan1_kernel(const int* __restrict__ cnt, int* __restrict__ offs,
                             int* __restrict__ bsum) {
    __shared__ int wsum[4];
    const int tid = threadIdx.x, lane = tid & 63, wid = tid >> 6;
    const int idx = blockIdx.x * 256 + tid;
    int v = (idx < N_NODES) ? cnt[idx] : 0;
    int x = v;
    #pragma unroll
    for (int d = 1; d < 64; d <<= 1) {
        int y = __shfl_up(x, d);
        if (lane >= d) x += y;
    }
    if (lane == 63) wsum[wid] = x;
    __syncthreads();
    int wpre = 0;
    for (int w = 0; w < wid; ++w) wpre += wsum[w];
    if (idx < N_NODES) offs[idx] = x - v + wpre;          // intra-block exclusive
    if (tid == 255) bsum[blockIdx.x] = wsum[0] + wsum[1] + wsum[2] + wsum[3];
}

__global__ void scan2_kernel(const int* __restrict__ bsum, int* __restrict__ boff,
                             int* __restrict__ offs) {
    __shared__ int wsum[4];
    const int tid = threadIdx.x, lane = tid & 63, wid = tid >> 6;
    int v = (tid < NBLK) ? bsum[tid] : 0;
    int x = v;
    #pragma unroll
    for (int d = 1; d < 64; d <<= 1) {
        int y = __shfl_up(x, d);
        if (lane >= d) x += y;
    }
    if (lane == 63) wsum[wid] = x;
    __syncthreads();
    int wpre = 0;
    for (int w = 0; w < wid; ++w) wpre += wsum[w];
    if (tid < NBLK) boff[tid] = x - v + wpre;
    if (tid == 255) offs[N_NODES] = wsum[0] + wsum[1] + wsum[2] + wsum[3];
}

__global__ void scan3_kernel(int* __restrict__ offs, const int* __restrict__ boff) {
    int idx = blockIdx.x * 256 + threadIdx.x;
    if (idx < N_NODES) offs[idx] += boff[blockIdx.x];
}

__global__ void scatter_kernel(const int* __restrict__ src, const int* __restrict__ dst,
                               const int* __restrict__ offs, int* __restrict__ cursor,
                               int* __restrict__ sorted_src) {
    int e = blockIdx.x * blockDim.x + threadIdx.x;
    if (e >= N_EDGES) return;
    int d = dst[e];
    int p = offs[d] + atomicAdd(&cursor[d], 1);
    sorted_src[p] = src[e];
}

// ---------------- mean aggregation: one wave per node, 4-deep gather ----------------
__global__ void agg_kernel(const float* __restrict__ x, const int* __restrict__ offs,
                           const int* __restrict__ sorted_src, float* __restrict__ mean) {
    int gw = (blockIdx.x * blockDim.x + threadIdx.x) >> 6;
    int lane = threadIdx.x & 63;
    if (gw >= N_NODES) return;
    int beg = __builtin_amdgcn_readfirstlane(offs[gw]);
    int end = __builtin_amdgcn_readfirstlane(offs[gw + 1]);
    float4 a0 = make_float4(0.f,0.f,0.f,0.f), a1 = a0, a2 = a0, a3 = a0;
    int k = beg;
    for (; k + 4 <= end; k += 4) {
        int s0 = __builtin_amdgcn_readfirstlane(sorted_src[k]);
        int s1 = __builtin_amdgcn_readfirstlane(sorted_src[k + 1]);
        int s2 = __builtin_amdgcn_readfirstlane(sorted_src[k + 2]);
        int s3 = __builtin_amdgcn_readfirstlane(sorted_src[k + 3]);
        float4 v0 = *reinterpret_cast<const float4*>(x + (size_t)s0 * D_IN + lane * 4);
        float4 v1 = *reinterpret_cast<const float4*>(x + (size_t)s1 * D_IN + lane * 4);
        float4 v2 = *reinterpret_cast<const float4*>(x + (size_t)s2 * D_IN + lane * 4);
        float4 v3 = *reinterpret_cast<const float4*>(x + (size_t)s3 * D_IN + lane * 4);
        a0.x += v0.x; a0.y += v0.y; a0.z += v0.z; a0.w += v0.w;
        a1.x += v1.x; a1.y += v1.y; a1.z += v1.z; a1.w += v1.w;
        a2.x += v2.x; a2.y += v2.y; a2.z += v2.z; a2.w += v2.w;
        a3.x += v3.x; a3.y += v3.y; a3.z += v3.z; a3.w += v3.w;
    }
    for (; k < end; ++k) {
        int s0 = __builtin_amdgcn_readfirstlane(sorted_src[k]);
        float4 v0 = *reinterpret_cast<const float4*>(x + (size_t)s0 * D_IN + lane * 4);
        a0.x += v0.x; a0.y += v0.y; a0.z += v0.z; a0.w += v0.w;
    }
    int c = end - beg;
    float inv = (c > 0) ? (1.0f / (float)c) : 0.0f;
    float4 o;
    o.x = (a0.x + a1.x + a2.x + a3.x) * inv;
    o.y = (a0.y + a1.y + a2.y + a3.y) * inv;
    o.z = (a0.z + a1.z + a2.z + a3.z) * inv;
    o.w = (a0.w + a1.w + a2.w + a3.w) * inv;
    *reinterpret_cast<float4*>(mean + (size_t)gw * D_IN + lane * 4) = o;
}

// ---------------- W prep: B' = [Wl;Wr] -> transposed bf16 hi/lo ----------------
__global__ void prepw_kernel(const float* __restrict__ Wl, const float* __restrict__ Wr,
                             unsigned short* __restrict__ BhT, unsigned short* __restrict__ BlT) {
    int idx = blockIdx.x * blockDim.x + threadIdx.x;   // 262144 total
    if (idx >= 512 * 512) return;
    int n = idx >> 9, k = idx & 511;
    float v = (k < 256) ? Wl[(size_t)k * D_HID + n] : Wr[(size_t)(k - 256) * D_HID + n];
    unsigned u = __float_as_uint(v);
    unsigned hi_aligned = (u + 0x7fffu + ((u >> 16) & 1u)) & 0xffff0000u;
    float hf = __uint_as_float(hi_aligned);
    float lo = v - hf;
    BhT[idx] = (unsigned short)(hi_aligned >> 16);
    BlT[idx] = (unsigned short)bf16_rne_bits(lo);
}

// ---------------- split-bf16 MFMA GEMM ----------------
#define GBM 128
#define GBN 128
#define GBK 32

// 16B slots; ((r>>1)&3)^g spreads 8 consecutive rows over all 8 bank-groups.
__device__ inline int lds_slot(int r, int g) { return r * 4 + (((r >> 1) & 3) ^ g); }

__global__ __launch_bounds__(256, 2) void gemm_mfma(
        const float* __restrict__ mean, const float* __restrict__ x,
        const unsigned short* __restrict__ BhT, const unsigned short* __restrict__ BlT,
        const float* __restrict__ bias, float* __restrict__ out) {
    __shared__ __align__(16) unsigned short Ah_s[GBM * GBK];  // 8KB each
    __shared__ __align__(16) unsigned short Al_s[GBM * GBK];
    __shared__ __align__(16) unsigned short Bh_s[GBN * GBK];  // [n][k] layout
    __shared__ __align__(16) unsigned short Bl_s[GBN * GBK];

    const int tid  = threadIdx.x;
    const int lane = tid & 63, wave = tid >> 6;
    const int wr = wave >> 1, wc = wave & 1;          // 2x2 waves of 64x64
    const int mtile = blockIdx.x >> 2;
    const int ntile = blockIdx.x & 3;
    const int row0 = mtile * GBM, col0 = ntile * GBN;

    const int ar  = tid >> 1;
    const int ach = tid & 1;
    const int agrow = row0 + ar;
    const bool aok = (agrow < N_NODES);

    const int fr = lane & 15, fg = lane >> 4;

    f32x4 acc[4][4];
    #pragma unroll
    for (int i = 0; i < 4; ++i)
        #pragma unroll
        for (int j = 0; j < 4; ++j) acc[i][j] = (f32x4)0.f;

    for (int k0 = 0; k0 < 512; k0 += GBK) {
        // ---- stage A: load 16 fp32, split to hi/lo bf16, swizzled ds_write
        {
            const int k0c = k0 + ach * 16;
            float f[16];
            if (aok) {
                const float* asrc = (k0c < 256)
                    ? (mean + (size_t)agrow * D_IN + k0c)
                    : (x    + (size_t)agrow * D_IN + (k0c - 256));
                float4 v0 = *reinterpret_cast<const float4*>(asrc + 0);
                float4 v1 = *reinterpret_cast<const float4*>(asrc + 4);
                float4 v2 = *reinterpret_cast<const float4*>(asrc + 8);
                float4 v3 = *reinterpret_cast<const float4*>(asrc + 12);
                f[0]=v0.x; f[1]=v0.y; f[2]=v0.z; f[3]=v0.w;
                f[4]=v1.x; f[5]=v1.y; f[6]=v1.z; f[7]=v1.w;
                f[8]=v2.x; f[9]=v2.y; f[10]=v2.z; f[11]=v2.w;
                f[12]=v3.x; f[13]=v3.y; f[14]=v3.z; f[15]=v3.w;
            } else {
                #pragma unroll
                for (int e = 0; e < 16; ++e) f[e] = 0.f;
            }
            unsigned h[16], l[16];
            #pragma unroll
            for (int e = 0; e < 16; ++e) {
                unsigned u = __float_as_uint(f[e]);
                unsigned ha = (u + 0x7fffu + ((u >> 16) & 1u)) & 0xffff0000u;
                h[e] = ha;
                float lo = f[e] - __uint_as_float(ha);
                l[e] = bf16_rne_bits(lo);
            }
            uint4 hv0, hv1, lv0, lv1;
            hv0.x = (h[1] & 0xffff0000u)  | (h[0] >> 16);
            hv0.y = (h[3] & 0xffff0000u)  | (h[2] >> 16);
            hv0.z = (h[5] & 0xffff0000u)  | (h[4] >> 16);
            hv0.w = (h[7] & 0xffff0000u)  | (h[6] >> 16);
            hv1.x = (h[9] & 0xffff0000u)  | (h[8] >> 16);
            hv1.y = (h[11] & 0xffff0000u) | (h[10] >> 16);
            hv1.z = (h[13] & 0xffff0000u) | (h[12] >> 16);
            hv1.w = (h[15] & 0xffff0000u) | (h[14] >> 16);
            lv0.x = (l[1] << 16) | l[0];
            lv0.y = (l[3] << 16) | l[2];
            lv0.z = (l[5] << 16) | l[4];
            lv0.w = (l[7] << 16) | l[6];
            lv1.x = (l[9] << 16) | l[8];
            lv1.y = (l[11] << 16) | l[10];
            lv1.z = (l[13] << 16) | l[12];
            lv1.w = (l[15] << 16) | l[14];
            const int g0 = 2 * ach, g1 = 2 * ach + 1;
            *reinterpret_cast<uint4*>(&Ah_s[lds_slot(ar, g0) * 8]) = hv0;
            *reinterpret_cast<uint4*>(&Ah_s[lds_slot(ar, g1) * 8]) = hv1;
            *reinterpret_cast<uint4*>(&Al_s[lds_slot(ar, g0) * 8]) = lv0;
            *reinterpret_cast<uint4*>(&Al_s[lds_slot(ar, g1) * 8]) = lv1;
        }
        // ---- stage B: copy bf16 tiles (hi & lo), swizzled
        #pragma unroll
        for (int i = 0; i < 2; ++i) {
            int s = i * 256 + tid;
            int br = s >> 2, bg = s & 3;
            size_t goff = (size_t)(col0 + br) * 512 + k0 + bg * 8;
            uint4 hb = *reinterpret_cast<const uint4*>(BhT + goff);
            uint4 lb = *reinterpret_cast<const uint4*>(BlT + goff);
            *reinterpret_cast<uint4*>(&Bh_s[lds_slot(br, bg) * 8]) = hb;
            *reinterpret_cast<uint4*>(&Bl_s[lds_slot(br, bg) * 8]) = lb;
        }
        __syncthreads();

        // ---- fragments + 48 MFMA (3 split-products x 16 tiles)
        bf16x8 ah[4], al[4], bh[4], bl[4];
        #pragma unroll
        for (int m = 0; m < 4; ++m) {
            int r = wr * 64 + m * 16 + fr;
            ah[m] = *reinterpret_cast<const bf16x8*>(&Ah_s[lds_slot(r, fg) * 8]);
            al[m] = *reinterpret_cast<const bf16x8*>(&Al_s[lds_slot(r, fg) * 8]);
        }
        #pragma unroll
        for (int n = 0; n < 4; ++n) {
            int r = wc * 64 + n * 16 + fr;
            bh[n] = *reinterpret_cast<const bf16x8*>(&Bh_s[lds_slot(r, fg) * 8]);
            bl[n] = *reinterpret_cast<const bf16x8*>(&Bl_s[lds_slot(r, fg) * 8]);
        }
        #pragma unroll
        for (int m = 0; m < 4; ++m)
            #pragma unroll
            for (int n = 0; n < 4; ++n) {
                acc[m][n] = __builtin_amdgcn_mfma_f32_16x16x32_bf16(ah[m], bh[n], acc[m][n], 0, 0, 0);
                acc[m][n] = __builtin_amdgcn_mfma_f32_16x16x32_bf16(al[m], bh[n], acc[m][n], 0, 0, 0);
                acc[m][n] = __builtin_amdgcn_mfma_f32_16x16x32_bf16(ah[m], bl[n], acc[m][n], 0, 0, 0);
            }
        __syncthreads();
    }

    // ---- epilogue: C/D layout col=lane&15, row=(lane>>4)*4+v  [m89-verified]
    float bv[4];
    #pragma unroll
    for (int n = 0; n < 4; ++n) bv[n] = bias[col0 + wc * 64 + n * 16 + fr];
    #pragma unroll
    for (int m = 0; m < 4; ++m) {
        #pragma unroll
        for (int v = 0; v < 4; ++v) {
            int grow = row0 + wr * 64 + m * 16 + fg * 4 + v;
            if (grow < N_NODES) {
                size_t base = (size_t)grow * D_HID + col0 + wc * 64 + fr;
                #pragma unroll
                for (int n = 0; n < 4; ++n)
                    out[base + n * 16] = acc[m][n][v] + bv[n];
            }
        }
    }
}

// ---------------- launcher ----------------
extern "C" void kernel_launch(void* const* d_in, const int* in_sizes, int n_in,
                              void* d_out, int out_size, void* d_ws, size_t ws_size,
                              hipStream_t stream) {
    const float* x    = (const float*)d_in[0];
    const void*  ei   = d_in[1];
    const float* Wl   = (const float*)d_in[2];
    const float* Wr   = (const float*)d_in[3];
    const float* bias = (const float*)d_in[4];
    float* out = (float*)d_out;

    char* ws = (char*)d_ws;
    int*   flag       = (int*)(ws + OFF_FLAG);
    int*   edges32    = (int*)(ws + OFF_EDGES);
    int*   src32      = edges32;
    int*   dst32      = edges32 + N_EDGES;
    int*   cnt        = (int*)(ws + OFF_CNT);
    int*   offs       = (int*)(ws + OFF_OFFS);
    int*   cursor     = (int*)(ws + OFF_CUR);
    int*   bsum       = (int*)(ws + OFF_BSUM);   // aliases cursor (dead until scatter)
    int*   boff       = (int*)(ws + OFF_BOFF);
    int*   sorted_src = (int*)(ws + OFF_SORT);
    float* mean       = (float*)(ws + OFF_MEAN);
    unsigned short* BhT = (unsigned short*)(ws + OFF_BHT);   // aliases edges32 (dead after scatter)
    unsigned short* BlT = (unsigned short*)(ws + OFF_BLT);

    hipMemsetAsync(cnt, 0, N_NODES * sizeof(int), stream);

    detect_kernel<<<1, 256, 0, stream>>>((const unsigned int*)ei, flag);
    convert_hist_kernel<<<(2 * N_EDGES + 255) / 256, 256, 0, stream>>>(ei, flag, edges32, cnt);
    scan1_kernel<<<NBLK, 256, 0, stream>>>(cnt, offs, bsum);
    scan2_kernel<<<1, 256, 0, stream>>>(bsum, boff, offs);
    scan3_kernel<<<NBLK, 256, 0, stream>>>(offs, boff);
    // cursor memset AFTER scans (bsum/boff alias the cursor region)
    hipMemsetAsync(cursor, 0, N_NODES * sizeof(int), stream);
    scatter_kernel<<<(N_EDGES + 255) / 256, 256, 0, stream>>>(src32, dst32, offs, cursor, sorted_src);
    // edges32 region is dead from here on -> prepw reuses it for BhT/BlT
    prepw_kernel<<<(512 * 512 + 255) / 256, 256, 0, stream>>>(Wl, Wr, BhT, BlT);
    agg_kernel<<<(N_NODES * 64 + 255) / 256, 256, 0, stream>>>(x, offs, sorted_src, mean);

    const int mtiles = (N_NODES + GBM - 1) / GBM;   // 391
    gemm_mfma<<<mtiles * 4, 256, 0, stream>>>(mean, x, BhT, BlT, bias, out);
}

// Round 5
// 394.887 us; speedup vs baseline: 2.7134x; 1.1038x over previous
//
#include <hip/hip_runtime.h>

#define N_NODES 50000
#define N_EDGES 800000
#define D_IN    256
#define D_HID   512
#define NBLK    196            // ceil(N_NODES/256)

typedef __attribute__((ext_vector_type(8))) short bf16x8;
typedef __attribute__((ext_vector_type(4))) float f32x4;
typedef __attribute__((ext_vector_type(8))) _Float16 f16x8;

// ---------------- workspace layout (peak 61,401,088 B — proven ≤ ws_size in R1/R3/R4) ----
constexpr size_t OFF_FLAG  = 0;                       // int flag (1 => edge_index is int64)
constexpr size_t OFF_EDGES = 256;                     // 2*N_EDGES ints: src[0..E), dst[E..2E)
constexpr size_t OFF_BHT   = OFF_EDGES;               // 512*512 bf16 — reuses edges32 AFTER scatter
constexpr size_t OFF_BLT   = OFF_BHT   + 524288;
constexpr size_t OFF_CNT   = OFF_EDGES + 6400000;     // N_NODES ints
constexpr size_t OFF_OFFS  = OFF_CNT   + 200192;      // N_NODES+1 ints
constexpr size_t OFF_CUR   = OFF_OFFS  + 200448;      // N_NODES ints (hosts bsum/boff pre-scatter)
constexpr size_t OFF_BSUM  = OFF_CUR;                 // NBLK ints
constexpr size_t OFF_BOFF  = OFF_CUR   + 1024;        // NBLK ints
constexpr size_t OFF_SORT  = OFF_CUR   + 200192;      // N_EDGES ints (src sorted by dst)
constexpr size_t OFF_XH    = OFF_SORT  + 3200000;     // x as fp16: 50000*256*2 = 25.6MB
constexpr size_t OFF_M16   = OFF_XH    + 25600000;    // mean as fp16: 25.6MB (ends 61,401,088)

// ---------------- helpers ----------------
__device__ inline unsigned bf16_rne_bits(float f) {   // returns bf16 in low 16
    unsigned u = __float_as_uint(f);
    return (u + 0x7fffu + ((u >> 16) & 1u)) >> 16;
}

// ---------------- dtype detection: int64 vs int32 edge_index ----------------
__global__ void detect_kernel(const unsigned int* __restrict__ ei, int* __restrict__ flag) {
    __shared__ int any;
    if (threadIdx.x == 0) any = 0;
    __syncthreads();
    int local = 0;
    for (int i = threadIdx.x; i < 4096; i += blockDim.x)
        local |= (ei[2 * i + 1] != 0u);
    if (local) any = 1;
    __syncthreads();
    if (threadIdx.x == 0) *flag = any ? 0 : 1;   // 1 => int64
}

// convert + fused dst-histogram (cnt must be zeroed before)
__global__ void convert_hist_kernel(const void* __restrict__ ei, const int* __restrict__ flag,
                                    int* __restrict__ edges32, int* __restrict__ cnt) {
    int i = blockIdx.x * blockDim.x + threadIdx.x;
    if (i >= 2 * N_EDGES) return;
    int v;
    if (*flag) v = (int)((const long long*)ei)[i];
    else       v = ((const int*)ei)[i];
    edges32[i] = v;
    if (i >= N_EDGES) atomicAdd(&cnt[v], 1);      // dst half
}

// ---------------- x -> fp16 copy (halves gather traffic) ----------------
__global__ void prepx_kernel(const float* __restrict__ x, f16x8* __restrict__ xh) {
    int i = blockIdx.x * 256 + threadIdx.x;            // 1,600,000 groups of 8
    if (i >= N_NODES * D_IN / 8) return;
    const float4* s = reinterpret_cast<const float4*>(x + (size_t)i * 8);
    float4 a = s[0], b = s[1];
    f16x8 o;
    o[0] = (_Float16)a.x; o[1] = (_Float16)a.y; o[2] = (_Float16)a.z; o[3] = (_Float16)a.w;
    o[4] = (_Float16)b.x; o[5] = (_Float16)b.y; o[6] = (_Float16)b.z; o[7] = (_Float16)b.w;
    xh[i] = o;
}

// ---------------- hierarchical scan: offs = exclusive_scan(cnt) ----------------
__global__ void scan1_kernel(const int* __restrict__ cnt, int* __restrict__ offs,
                             int* __restrict__ bsum) {
    __shared__ int wsum[4];
    const int tid = threadIdx.x, lane = tid & 63, wid = tid >> 6;
    const int idx = blockIdx.x * 256 + tid;
    int v = (idx < N_NODES) ? cnt[idx] : 0;
    int x = v;
    #pragma unroll
    for (int d = 1; d < 64; d <<= 1) {
        int y = __shfl_up(x, d);
        if (lane >= d) x += y;
    }
    if (lane == 63) wsum[wid] = x;
    __syncthreads();
    int wpre = 0;
    for (int w = 0; w < wid; ++w) wpre += wsum[w];
    if (idx < N_NODES) offs[idx] = x - v + wpre;          // intra-block exclusive
    if (tid == 255) bsum[blockIdx.x] = wsum[0] + wsum[1] + wsum[2] + wsum[3];
}

__global__ void scan2_kernel(const int* __restrict__ bsum, int* __restrict__ boff,
                             int* __restrict__ offs) {
    __shared__ int wsum[4];
    const int tid = threadIdx.x, lane = tid & 63, wid = tid >> 6;
    int v = (tid < NBLK) ? bsum[tid] : 0;
    int x = v;
    #pragma unroll
    for (int d = 1; d < 64; d <<= 1) {
        int y = __shfl_up(x, d);
        if (lane >= d) x += y;
    }
    if (lane == 63) wsum[wid] = x;
    __syncthreads();
    int wpre = 0;
    for (int w = 0; w < wid; ++w) wpre += wsum[w];
    if (tid < NBLK) boff[tid] = x - v + wpre;
    if (tid == 255) offs[N_NODES] = wsum[0] + wsum[1] + wsum[2] + wsum[3];
}

__global__ void scan3_kernel(int* __restrict__ offs, const int* __restrict__ boff) {
    int idx = blockIdx.x * 256 + threadIdx.x;
    if (idx < N_NODES) offs[idx] += boff[blockIdx.x];
}

__global__ void scatter_kernel(const int* __restrict__ src, const int* __restrict__ dst,
                               const int* __restrict__ offs, int* __restrict__ cursor,
                               int* __restrict__ sorted_src) {
    int e = blockIdx.x * blockDim.x + threadIdx.x;
    if (e >= N_EDGES) return;
    int d = dst[e];
    int p = offs[d] + atomicAdd(&cursor[d], 1);
    sorted_src[p] = src[e];
}

// ---------------- mean aggregation: one wave per node, fp16 gather ----------------
// Half-waves of 32 lanes each handle one edge-row per load (8 fp16/lane = 16B);
// 4 edges in flight; cross-half combine via shfl(lane^32); mean stored fp16.
__global__ void agg_kernel(const f16x8* __restrict__ xh, const int* __restrict__ offs,
                           const int* __restrict__ sorted_src, f16x8* __restrict__ m16) {
    int gw = (blockIdx.x * blockDim.x + threadIdx.x) >> 6;
    int lane = threadIdx.x & 63;
    if (gw >= N_NODES) return;
    int beg = __builtin_amdgcn_readfirstlane(offs[gw]);
    int end = __builtin_amdgcn_readfirstlane(offs[gw + 1]);
    const int half = lane >> 5, cb = lane & 31;       // cb: which 8-col group
    float a0[8] = {0,0,0,0,0,0,0,0}, a1[8] = {0,0,0,0,0,0,0,0};
    int k = beg;
    for (; k + 4 <= end; k += 4) {
        int s0 = sorted_src[k + half];
        int s1 = sorted_src[k + 2 + half];
        f16x8 v0 = xh[(size_t)s0 * 32 + cb];
        f16x8 v1 = xh[(size_t)s1 * 32 + cb];
        #pragma unroll
        for (int j = 0; j < 8; ++j) { a0[j] += (float)v0[j]; a1[j] += (float)v1[j]; }
    }
    if (k + 2 <= end) {
        int s0 = sorted_src[k + half];
        f16x8 v0 = xh[(size_t)s0 * 32 + cb];
        #pragma unroll
        for (int j = 0; j < 8; ++j) a0[j] += (float)v0[j];
        k += 2;
    }
    if (k < end && half == 0) {                       // odd tail: lower half only
        int s0 = sorted_src[k];
        f16x8 v0 = xh[(size_t)s0 * 32 + cb];
        #pragma unroll
        for (int j = 0; j < 8; ++j) a0[j] += (float)v0[j];
    }
    int c = end - beg;
    float inv = (c > 0) ? (1.0f / (float)c) : 0.0f;
    float tot[8];
    #pragma unroll
    for (int j = 0; j < 8; ++j) tot[j] = a0[j] + a1[j];
    #pragma unroll
    for (int j = 0; j < 8; ++j) tot[j] += __shfl(tot[j], lane ^ 32, 64);
    f16x8 o;
    #pragma unroll
    for (int j = 0; j < 8; ++j) o[j] = (_Float16)(tot[j] * inv);
    if (half == 0) m16[(size_t)gw * 32 + cb] = o;
}

// ---------------- W prep: B' = [Wl;Wr] -> transposed bf16 hi/lo ----------------
__global__ void prepw_kernel(const float* __restrict__ Wl, const float* __restrict__ Wr,
                             unsigned short* __restrict__ BhT, unsigned short* __restrict__ BlT) {
    int idx = blockIdx.x * blockDim.x + threadIdx.x;   // 262144 total
    if (idx >= 512 * 512) return;
    int n = idx >> 9, k = idx & 511;
    float v = (k < 256) ? Wl[(size_t)k * D_HID + n] : Wr[(size_t)(k - 256) * D_HID + n];
    unsigned u = __float_as_uint(v);
    unsigned hi_aligned = (u + 0x7fffu + ((u >> 16) & 1u)) & 0xffff0000u;
    float hf = __uint_as_float(hi_aligned);
    float lo = v - hf;
    BhT[idx] = (unsigned short)(hi_aligned >> 16);
    BlT[idx] = (unsigned short)bf16_rne_bits(lo);
}

// ---------------- split-bf16 MFMA GEMM ----------------
// C[M,512] = [mean16 | x] @ B + bias; A-half 0 from fp16 mean, A-half 1 from fp32 x.
#define GBM 128
#define GBN 128
#define GBK 32

// 16B slots; ((r>>1)&3)^g spreads 8 consecutive rows over all 8 bank-groups.
__device__ inline int lds_slot(int r, int g) { return r * 4 + (((r >> 1) & 3) ^ g); }

__global__ __launch_bounds__(256, 2) void gemm_mfma(
        const _Float16* __restrict__ mean16, const float* __restrict__ x,
        const unsigned short* __restrict__ BhT, const unsigned short* __restrict__ BlT,
        const float* __restrict__ bias, float* __restrict__ out) {
    __shared__ __align__(16) unsigned short Ah_s[GBM * GBK];  // 8KB each
    __shared__ __align__(16) unsigned short Al_s[GBM * GBK];
    __shared__ __align__(16) unsigned short Bh_s[GBN * GBK];  // [n][k] layout
    __shared__ __align__(16) unsigned short Bl_s[GBN * GBK];

    const int tid  = threadIdx.x;
    const int lane = tid & 63, wave = tid >> 6;
    const int wr = wave >> 1, wc = wave & 1;          // 2x2 waves of 64x64
    const int mtile = blockIdx.x >> 2;
    const int ntile = blockIdx.x & 3;
    const int row0 = mtile * GBM, col0 = ntile * GBN;

    const int ar  = tid >> 1;
    const int ach = tid & 1;
    const int agrow = row0 + ar;
    const bool aok = (agrow < N_NODES);

    const int fr = lane & 15, fg = lane >> 4;

    f32x4 acc[4][4];
    #pragma unroll
    for (int i = 0; i < 4; ++i)
        #pragma unroll
        for (int j = 0; j < 4; ++j) acc[i][j] = (f32x4)0.f;

    for (int k0 = 0; k0 < 512; k0 += GBK) {
        // ---- stage A: load 16 values, split to hi/lo bf16, swizzled ds_write
        {
            const int k0c = k0 + ach * 16;
            float f[16];
            if (aok) {
                if (k0c < 256) {
                    const f16x8* mp = reinterpret_cast<const f16x8*>(
                        mean16 + (size_t)agrow * D_IN + k0c);
                    f16x8 p0 = mp[0], p1 = mp[1];
                    #pragma unroll
                    for (int e = 0; e < 8; ++e) { f[e] = (float)p0[e]; f[e + 8] = (float)p1[e]; }
                } else {
                    const float* asrc = x + (size_t)agrow * D_IN + (k0c - 256);
                    float4 v0 = *reinterpret_cast<const float4*>(asrc + 0);
                    float4 v1 = *reinterpret_cast<const float4*>(asrc + 4);
                    float4 v2 = *reinterpret_cast<const float4*>(asrc + 8);
                    float4 v3 = *reinterpret_cast<const float4*>(asrc + 12);
                    f[0]=v0.x; f[1]=v0.y; f[2]=v0.z; f[3]=v0.w;
                    f[4]=v1.x; f[5]=v1.y; f[6]=v1.z; f[7]=v1.w;
                    f[8]=v2.x; f[9]=v2.y; f[10]=v2.z; f[11]=v2.w;
                    f[12]=v3.x; f[13]=v3.y; f[14]=v3.z; f[15]=v3.w;
                }
            } else {
                #pragma unroll
                for (int e = 0; e < 16; ++e) f[e] = 0.f;
            }
            unsigned h[16], l[16];
            #pragma unroll
            for (int e = 0; e < 16; ++e) {
                unsigned u = __float_as_uint(f[e]);
                unsigned ha = (u + 0x7fffu + ((u >> 16) & 1u)) & 0xffff0000u;
                h[e] = ha;
                float lo = f[e] - __uint_as_float(ha);
                l[e] = bf16_rne_bits(lo);
            }
            uint4 hv0, hv1, lv0, lv1;
            hv0.x = (h[1] & 0xffff0000u)  | (h[0] >> 16);
            hv0.y = (h[3] & 0xffff0000u)  | (h[2] >> 16);
            hv0.z = (h[5] & 0xffff0000u)  | (h[4] >> 16);
            hv0.w = (h[7] & 0xffff0000u)  | (h[6] >> 16);
            hv1.x = (h[9] & 0xffff0000u)  | (h[8] >> 16);
            hv1.y = (h[11] & 0xffff0000u) | (h[10] >> 16);
            hv1.z = (h[13] & 0xffff0000u) | (h[12] >> 16);
            hv1.w = (h[15] & 0xffff0000u) | (h[14] >> 16);
            lv0.x = (l[1] << 16) | l[0];
            lv0.y = (l[3] << 16) | l[2];
            lv0.z = (l[5] << 16) | l[4];
            lv0.w = (l[7] << 16) | l[6];
            lv1.x = (l[9] << 16) | l[8];
            lv1.y = (l[11] << 16) | l[10];
            lv1.z = (l[13] << 16) | l[12];
            lv1.w = (l[15] << 16) | l[14];
            const int g0 = 2 * ach, g1 = 2 * ach + 1;
            *reinterpret_cast<uint4*>(&Ah_s[lds_slot(ar, g0) * 8]) = hv0;
            *reinterpret_cast<uint4*>(&Ah_s[lds_slot(ar, g1) * 8]) = hv1;
            *reinterpret_cast<uint4*>(&Al_s[lds_slot(ar, g0) * 8]) = lv0;
            *reinterpret_cast<uint4*>(&Al_s[lds_slot(ar, g1) * 8]) = lv1;
        }
        // ---- stage B: copy bf16 tiles (hi & lo), swizzled
        #pragma unroll
        for (int i = 0; i < 2; ++i) {
            int s = i * 256 + tid;
            int br = s >> 2, bg = s & 3;
            size_t goff = (size_t)(col0 + br) * 512 + k0 + bg * 8;
            uint4 hb = *reinterpret_cast<const uint4*>(BhT + goff);
            uint4 lb = *reinterpret_cast<const uint4*>(BlT + goff);
            *reinterpret_cast<uint4*>(&Bh_s[lds_slot(br, bg) * 8]) = hb;
            *reinterpret_cast<uint4*>(&Bl_s[lds_slot(br, bg) * 8]) = lb;
        }
        __syncthreads();

        // ---- fragments + 48 MFMA (3 split-products x 16 tiles)
        bf16x8 ah[4], al[4], bh[4], bl[4];
        #pragma unroll
        for (int m = 0; m < 4; ++m) {
            int r = wr * 64 + m * 16 + fr;
            ah[m] = *reinterpret_cast<const bf16x8*>(&Ah_s[lds_slot(r, fg) * 8]);
            al[m] = *reinterpret_cast<const bf16x8*>(&Al_s[lds_slot(r, fg) * 8]);
        }
        #pragma unroll
        for (int n = 0; n < 4; ++n) {
            int r = wc * 64 + n * 16 + fr;
            bh[n] = *reinterpret_cast<const bf16x8*>(&Bh_s[lds_slot(r, fg) * 8]);
            bl[n] = *reinterpret_cast<const bf16x8*>(&Bl_s[lds_slot(r, fg) * 8]);
        }
        #pragma unroll
        for (int m = 0; m < 4; ++m)
            #pragma unroll
            for (int n = 0; n < 4; ++n) {
                acc[m][n] = __builtin_amdgcn_mfma_f32_16x16x32_bf16(ah[m], bh[n], acc[m][n], 0, 0, 0);
                acc[m][n] = __builtin_amdgcn_mfma_f32_16x16x32_bf16(al[m], bh[n], acc[m][n], 0, 0, 0);
                acc[m][n] = __builtin_amdgcn_mfma_f32_16x16x32_bf16(ah[m], bl[n], acc[m][n], 0, 0, 0);
            }
        __syncthreads();
    }

    // ---- epilogue: C/D layout col=lane&15, row=(lane>>4)*4+v  [m89-verified]
    float bv[4];
    #pragma unroll
    for (int n = 0; n < 4; ++n) bv[n] = bias[col0 + wc * 64 + n * 16 + fr];
    #pragma unroll
    for (int m = 0; m < 4; ++m) {
        #pragma unroll
        for (int v = 0; v < 4; ++v) {
            int grow = row0 + wr * 64 + m * 16 + fg * 4 + v;
            if (grow < N_NODES) {
                size_t base = (size_t)grow * D_HID + col0 + wc * 64 + fr;
                #pragma unroll
                for (int n = 0; n < 4; ++n)
                    out[base + n * 16] = acc[m][n][v] + bv[n];
            }
        }
    }
}

// ---------------- launcher ----------------
extern "C" void kernel_launch(void* const* d_in, const int* in_sizes, int n_in,
                              void* d_out, int out_size, void* d_ws, size_t ws_size,
                              hipStream_t stream) {
    const float* x    = (const float*)d_in[0];
    const void*  ei   = d_in[1];
    const float* Wl   = (const float*)d_in[2];
    const float* Wr   = (const float*)d_in[3];
    const float* bias = (const float*)d_in[4];
    float* out = (float*)d_out;

    char* ws = (char*)d_ws;
    int*   flag       = (int*)(ws + OFF_FLAG);
    int*   edges32    = (int*)(ws + OFF_EDGES);
    int*   src32      = edges32;
    int*   dst32      = edges32 + N_EDGES;
    int*   cnt        = (int*)(ws + OFF_CNT);
    int*   offs       = (int*)(ws + OFF_OFFS);
    int*   cursor     = (int*)(ws + OFF_CUR);
    int*   bsum       = (int*)(ws + OFF_BSUM);   // aliases cursor (dead until scatter)
    int*   boff       = (int*)(ws + OFF_BOFF);
    int*   sorted_src = (int*)(ws + OFF_SORT);
    f16x8* xh         = (f16x8*)(ws + OFF_XH);
    f16x8* m16        = (f16x8*)(ws + OFF_M16);
    unsigned short* BhT = (unsigned short*)(ws + OFF_BHT);   // aliases edges32 (dead after scatter)
    unsigned short* BlT = (unsigned short*)(ws + OFF_BLT);

    hipMemsetAsync(cnt, 0, N_NODES * sizeof(int), stream);

    detect_kernel<<<1, 256, 0, stream>>>((const unsigned int*)ei, flag);
    convert_hist_kernel<<<(2 * N_EDGES + 255) / 256, 256, 0, stream>>>(ei, flag, edges32, cnt);
    prepx_kernel<<<(N_NODES * D_IN / 8 + 255) / 256, 256, 0, stream>>>(x, xh);
    scan1_kernel<<<NBLK, 256, 0, stream>>>(cnt, offs, bsum);
    scan2_kernel<<<1, 256, 0, stream>>>(bsum, boff, offs);
    scan3_kernel<<<NBLK, 256, 0, stream>>>(offs, boff);
    // cursor memset AFTER scans (bsum/boff alias the cursor region)
    hipMemsetAsync(cursor, 0, N_NODES * sizeof(int), stream);
    scatter_kernel<<<(N_EDGES + 255) / 256, 256, 0, stream>>>(src32, dst32, offs, cursor, sorted_src);
    // edges32 region is dead from here on -> prepw reuses it for BhT/BlT
    prepw_kernel<<<(512 * 512 + 255) / 256, 256, 0, stream>>>(Wl, Wr, BhT, BlT);
    agg_kernel<<<(N_NODES * 64 + 255) / 256, 256, 0, stream>>>(xh, offs, sorted_src, m16);

    const int mtiles = (N_NODES + GBM - 1) / GBM;   // 391
    gemm_mfma<<<mtiles * 4, 256, 0, stream>>>((const _Float16*)m16, x, BhT, BlT, bias, out);
}

// Round 6
// 355.056 us; speedup vs baseline: 3.0178x; 1.1122x over previous
//
#include <hip/hip_runtime.h>

#define N_NODES 50000
#define N_EDGES 800000
#define D_IN    256
#define D_HID   512
#define NBLK    196            // ceil(N_NODES/256)

typedef __attribute__((ext_vector_type(8))) _Float16 f16x8;
typedef __attribute__((ext_vector_type(4))) float f32x4;

// ---------------- workspace layout (peak 61,401,088 B — proven ≤ ws_size) ----------------
constexpr size_t OFF_FLAG  = 0;                       // int flag (1 => edge_index is int64)
constexpr size_t OFF_EDGES = 256;                     // 2*N_EDGES ints: src[0..E), dst[E..2E)
constexpr size_t OFF_BT    = OFF_EDGES;               // 512*512 fp16 B^T — reuses edges32 AFTER scatter
constexpr size_t OFF_CNT   = OFF_EDGES + 6400000;     // N_NODES ints
constexpr size_t OFF_OFFS  = OFF_CNT   + 200192;      // N_NODES+1 ints
constexpr size_t OFF_CUR   = OFF_OFFS  + 200448;      // N_NODES ints (hosts bsum/boff pre-scatter)
constexpr size_t OFF_BSUM  = OFF_CUR;                 // NBLK ints
constexpr size_t OFF_BOFF  = OFF_CUR   + 1024;        // NBLK ints
constexpr size_t OFF_SORT  = OFF_CUR   + 200192;      // N_EDGES ints (src sorted by dst)
constexpr size_t OFF_XH    = OFF_SORT  + 3200000;     // x as fp16: 25.6MB
constexpr size_t OFF_M16   = OFF_XH    + 25600000;    // mean as fp16: 25.6MB (ends 61,401,088)

// ---------------- dtype detection: int64 vs int32 edge_index ----------------
__global__ void detect_kernel(const unsigned int* __restrict__ ei, int* __restrict__ flag) {
    __shared__ int any;
    if (threadIdx.x == 0) any = 0;
    __syncthreads();
    int local = 0;
    for (int i = threadIdx.x; i < 4096; i += blockDim.x)
        local |= (ei[2 * i + 1] != 0u);
    if (local) any = 1;
    __syncthreads();
    if (threadIdx.x == 0) *flag = any ? 0 : 1;   // 1 => int64
}

// convert + fused dst-histogram (cnt must be zeroed before)
__global__ void convert_hist_kernel(const void* __restrict__ ei, const int* __restrict__ flag,
                                    int* __restrict__ edges32, int* __restrict__ cnt) {
    int i = blockIdx.x * blockDim.x + threadIdx.x;
    if (i >= 2 * N_EDGES) return;
    int v;
    if (*flag) v = (int)((const long long*)ei)[i];
    else       v = ((const int*)ei)[i];
    edges32[i] = v;
    if (i >= N_EDGES) atomicAdd(&cnt[v], 1);      // dst half
}

// ---------------- x -> fp16 copy (halves gather traffic) ----------------
__global__ void prepx_kernel(const float* __restrict__ x, f16x8* __restrict__ xh) {
    int i = blockIdx.x * 256 + threadIdx.x;            // 1,600,000 groups of 8
    if (i >= N_NODES * D_IN / 8) return;
    const float4* s = reinterpret_cast<const float4*>(x + (size_t)i * 8);
    float4 a = s[0], b = s[1];
    f16x8 o;
    o[0] = (_Float16)a.x; o[1] = (_Float16)a.y; o[2] = (_Float16)a.z; o[3] = (_Float16)a.w;
    o[4] = (_Float16)b.x; o[5] = (_Float16)b.y; o[6] = (_Float16)b.z; o[7] = (_Float16)b.w;
    xh[i] = o;
}

// ---------------- hierarchical scan: offs = exclusive_scan(cnt) ----------------
__global__ void scan1_kernel(const int* __restrict__ cnt, int* __restrict__ offs,
                             int* __restrict__ bsum) {
    __shared__ int wsum[4];
    const int tid = threadIdx.x, lane = tid & 63, wid = tid >> 6;
    const int idx = blockIdx.x * 256 + tid;
    int v = (idx < N_NODES) ? cnt[idx] : 0;
    int x = v;
    #pragma unroll
    for (int d = 1; d < 64; d <<= 1) {
        int y = __shfl_up(x, d);
        if (lane >= d) x += y;
    }
    if (lane == 63) wsum[wid] = x;
    __syncthreads();
    int wpre = 0;
    for (int w = 0; w < wid; ++w) wpre += wsum[w];
    if (idx < N_NODES) offs[idx] = x - v + wpre;          // intra-block exclusive
    if (tid == 255) bsum[blockIdx.x] = wsum[0] + wsum[1] + wsum[2] + wsum[3];
}

__global__ void scan2_kernel(const int* __restrict__ bsum, int* __restrict__ boff,
                             int* __restrict__ offs) {
    __shared__ int wsum[4];
    const int tid = threadIdx.x, lane = tid & 63, wid = tid >> 6;
    int v = (tid < NBLK) ? bsum[tid] : 0;
    int x = v;
    #pragma unroll
    for (int d = 1; d < 64; d <<= 1) {
        int y = __shfl_up(x, d);
        if (lane >= d) x += y;
    }
    if (lane == 63) wsum[wid] = x;
    __syncthreads();
    int wpre = 0;
    for (int w = 0; w < wid; ++w) wpre += wsum[w];
    if (tid < NBLK) boff[tid] = x - v + wpre;
    if (tid == 255) offs[N_NODES] = wsum[0] + wsum[1] + wsum[2] + wsum[3];
}

__global__ void scan3_kernel(int* __restrict__ offs, const int* __restrict__ boff) {
    int idx = blockIdx.x * 256 + threadIdx.x;
    if (idx < N_NODES) offs[idx] += boff[blockIdx.x];
}

__global__ void scatter_kernel(const int* __restrict__ src, const int* __restrict__ dst,
                               const int* __restrict__ offs, int* __restrict__ cursor,
                               int* __restrict__ sorted_src) {
    int e = blockIdx.x * blockDim.x + threadIdx.x;
    if (e >= N_EDGES) return;
    int d = dst[e];
    int p = offs[d] + atomicAdd(&cursor[d], 1);
    sorted_src[p] = src[e];
}

// ---------------- mean aggregation: one wave per node, fp16 gather ----------------
__global__ void agg_kernel(const f16x8* __restrict__ xh, const int* __restrict__ offs,
                           const int* __restrict__ sorted_src, f16x8* __restrict__ m16) {
    int gw = (blockIdx.x * blockDim.x + threadIdx.x) >> 6;
    int lane = threadIdx.x & 63;
    if (gw >= N_NODES) return;
    int beg = __builtin_amdgcn_readfirstlane(offs[gw]);
    int end = __builtin_amdgcn_readfirstlane(offs[gw + 1]);
    const int half = lane >> 5, cb = lane & 31;       // cb: which 8-col group
    float a0[8] = {0,0,0,0,0,0,0,0}, a1[8] = {0,0,0,0,0,0,0,0};
    int k = beg;
    for (; k + 4 <= end; k += 4) {
        int s0 = sorted_src[k + half];
        int s1 = sorted_src[k + 2 + half];
        f16x8 v0 = xh[(size_t)s0 * 32 + cb];
        f16x8 v1 = xh[(size_t)s1 * 32 + cb];
        #pragma unroll
        for (int j = 0; j < 8; ++j) { a0[j] += (float)v0[j]; a1[j] += (float)v1[j]; }
    }
    if (k + 2 <= end) {
        int s0 = sorted_src[k + half];
        f16x8 v0 = xh[(size_t)s0 * 32 + cb];
        #pragma unroll
        for (int j = 0; j < 8; ++j) a0[j] += (float)v0[j];
        k += 2;
    }
    if (k < end && half == 0) {                       // odd tail: lower half only
        int s0 = sorted_src[k];
        f16x8 v0 = xh[(size_t)s0 * 32 + cb];
        #pragma unroll
        for (int j = 0; j < 8; ++j) a0[j] += (float)v0[j];
    }
    int c = end - beg;
    float inv = (c > 0) ? (1.0f / (float)c) : 0.0f;
    float tot[8];
    #pragma unroll
    for (int j = 0; j < 8; ++j) tot[j] = a0[j] + a1[j];
    #pragma unroll
    for (int j = 0; j < 8; ++j) tot[j] += __shfl(tot[j], lane ^ 32, 64);
    f16x8 o;
    #pragma unroll
    for (int j = 0; j < 8; ++j) o[j] = (_Float16)(tot[j] * inv);
    if (half == 0) m16[(size_t)gw * 32 + cb] = o;
}

// ---------------- W prep: B^T = [Wl;Wr]^T as fp16 ----------------
__global__ void prepw_kernel(const float* __restrict__ Wl, const float* __restrict__ Wr,
                             _Float16* __restrict__ BT) {
    int idx = blockIdx.x * blockDim.x + threadIdx.x;   // 262144 total
    if (idx >= 512 * 512) return;
    int n = idx >> 9, k = idx & 511;
    float v = (k < 256) ? Wl[(size_t)k * D_HID + n] : Wr[(size_t)(k - 256) * D_HID + n];
    BT[idx] = (_Float16)v;
}

// ---------------- single-pass fp16 MFMA GEMM ----------------
// C[M,512] = [mean16 | xh] @ B + bias; A,B fp16, fp32 accumulate.
#define GBM 128
#define GBN 128
#define GBK 32

// 16B slots; ((r>>1)&3)^g spreads 8 consecutive rows over all 8 bank-groups.
__device__ inline int lds_slot(int r, int g) { return r * 4 + (((r >> 1) & 3) ^ g); }

__global__ __launch_bounds__(256, 3) void gemm_f16(
        const _Float16* __restrict__ mean16, const _Float16* __restrict__ xh,
        const _Float16* __restrict__ BT, const float* __restrict__ bias,
        float* __restrict__ out) {
    __shared__ __align__(16) _Float16 A_s[GBM * GBK];  // 8KB
    __shared__ __align__(16) _Float16 B_s[GBN * GBK];  // 8KB ([n][k] layout)

    const int tid  = threadIdx.x;
    const int lane = tid & 63, wave = tid >> 6;
    const int wr = wave >> 1, wc = wave & 1;          // 2x2 waves of 64x64
    const int mtile = blockIdx.x >> 2;                // ntile fastest: 4 blocks share A panel
    const int ntile = blockIdx.x & 3;
    const int row0 = mtile * GBM, col0 = ntile * GBN;

    // staging map: thread -> (row, 16-col half)
    const int sr = tid >> 1, sh = tid & 1;
    const int agrow = row0 + sr;
    const bool aok = (agrow < N_NODES);

    const int fr = lane & 15, fg = lane >> 4;

    f32x4 acc[4][4];
    #pragma unroll
    for (int i = 0; i < 4; ++i)
        #pragma unroll
        for (int j = 0; j < 4; ++j) acc[i][j] = (f32x4)0.f;

    for (int k0 = 0; k0 < 512; k0 += GBK) {
        // ---- stage A: 32B/thread straight fp16 copy (no conversion)
        {
            const int k0c = k0 + sh * 16;              // always entirely in one region
            uint4 v0 = make_uint4(0, 0, 0, 0), v1 = v0;
            if (aok) {
                const _Float16* asrc = (k0c < 256)
                    ? (mean16 + (size_t)agrow * D_IN + k0c)
                    : (xh     + (size_t)agrow * D_IN + (k0c - 256));
                v0 = *reinterpret_cast<const uint4*>(asrc);
                v1 = *reinterpret_cast<const uint4*>(asrc + 8);
            }
            const int g0 = 2 * sh;
            *reinterpret_cast<uint4*>(&A_s[lds_slot(sr, g0) * 8])     = v0;
            *reinterpret_cast<uint4*>(&A_s[lds_slot(sr, g0 + 1) * 8]) = v1;
        }
        // ---- stage B: 32B/thread fp16 copy
        {
            const _Float16* bsrc = BT + (size_t)(col0 + sr) * 512 + k0 + sh * 16;
            uint4 v0 = *reinterpret_cast<const uint4*>(bsrc);
            uint4 v1 = *reinterpret_cast<const uint4*>(bsrc + 8);
            const int g0 = 2 * sh;
            *reinterpret_cast<uint4*>(&B_s[lds_slot(sr, g0) * 8])     = v0;
            *reinterpret_cast<uint4*>(&B_s[lds_slot(sr, g0 + 1) * 8]) = v1;
        }
        __syncthreads();

        // ---- fragments + 16 MFMA
        f16x8 av[4], bv[4];
        #pragma unroll
        for (int m = 0; m < 4; ++m) {
            int r = wr * 64 + m * 16 + fr;
            av[m] = *reinterpret_cast<const f16x8*>(&A_s[lds_slot(r, fg) * 8]);
        }
        #pragma unroll
        for (int n = 0; n < 4; ++n) {
            int r = wc * 64 + n * 16 + fr;
            bv[n] = *reinterpret_cast<const f16x8*>(&B_s[lds_slot(r, fg) * 8]);
        }
        #pragma unroll
        for (int m = 0; m < 4; ++m)
            #pragma unroll
            for (int n = 0; n < 4; ++n)
                acc[m][n] = __builtin_amdgcn_mfma_f32_16x16x32_f16(av[m], bv[n], acc[m][n], 0, 0, 0);
        __syncthreads();
    }

    // ---- epilogue: C/D layout col=lane&15, row=(lane>>4)*4+v  [m89-verified]
    float bvv[4];
    #pragma unroll
    for (int n = 0; n < 4; ++n) bvv[n] = bias[col0 + wc * 64 + n * 16 + fr];
    #pragma unroll
    for (int m = 0; m < 4; ++m) {
        #pragma unroll
        for (int v = 0; v < 4; ++v) {
            int grow = row0 + wr * 64 + m * 16 + fg * 4 + v;
            if (grow < N_NODES) {
                size_t base = (size_t)grow * D_HID + col0 + wc * 64 + fr;
                #pragma unroll
                for (int n = 0; n < 4; ++n)
                    out[base + n * 16] = acc[m][n][v] + bvv[n];
            }
        }
    }
}

// ---------------- launcher ----------------
extern "C" void kernel_launch(void* const* d_in, const int* in_sizes, int n_in,
                              void* d_out, int out_size, void* d_ws, size_t ws_size,
                              hipStream_t stream) {
    const float* x    = (const float*)d_in[0];
    const void*  ei   = d_in[1];
    const float* Wl   = (const float*)d_in[2];
    const float* Wr   = (const float*)d_in[3];
    const float* bias = (const float*)d_in[4];
    float* out = (float*)d_out;

    char* ws = (char*)d_ws;
    int*   flag       = (int*)(ws + OFF_FLAG);
    int*   edges32    = (int*)(ws + OFF_EDGES);
    int*   src32      = edges32;
    int*   dst32      = edges32 + N_EDGES;
    int*   cnt        = (int*)(ws + OFF_CNT);
    int*   offs       = (int*)(ws + OFF_OFFS);
    int*   cursor     = (int*)(ws + OFF_CUR);
    int*   bsum       = (int*)(ws + OFF_BSUM);   // aliases cursor (dead until scatter)
    int*   boff      = (int*)(ws + OFF_BOFF);
    int*   sorted_src = (int*)(ws + OFF_SORT);
    f16x8* xh         = (f16x8*)(ws + OFF_XH);
    f16x8* m16        = (f16x8*)(ws + OFF_M16);
    _Float16* BT      = (_Float16*)(ws + OFF_BT);   // aliases edges32 (dead after scatter)

    hipMemsetAsync(cnt, 0, N_NODES * sizeof(int), stream);

    detect_kernel<<<1, 256, 0, stream>>>((const unsigned int*)ei, flag);
    convert_hist_kernel<<<(2 * N_EDGES + 255) / 256, 256, 0, stream>>>(ei, flag, edges32, cnt);
    prepx_kernel<<<(N_NODES * D_IN / 8 + 255) / 256, 256, 0, stream>>>(x, xh);
    scan1_kernel<<<NBLK, 256, 0, stream>>>(cnt, offs, bsum);
    scan2_kernel<<<1, 256, 0, stream>>>(bsum, boff, offs);
    scan3_kernel<<<NBLK, 256, 0, stream>>>(offs, boff);
    // cursor memset AFTER scans (bsum/boff alias the cursor region)
    hipMemsetAsync(cursor, 0, N_NODES * sizeof(int), stream);
    scatter_kernel<<<(N_EDGES + 255) / 256, 256, 0, stream>>>(src32, dst32, offs, cursor, sorted_src);
    // edges32 region is dead from here on -> prepw reuses it for BT
    prepw_kernel<<<(512 * 512 + 255) / 256, 256, 0, stream>>>(Wl, Wr, BT);
    agg_kernel<<<(N_NODES * 64 + 255) / 256, 256, 0, stream>>>(xh, offs, sorted_src, m16);

    const int mtiles = (N_NODES + GBM - 1) / GBM;   // 391
    gemm_f16<<<mtiles * 4, 256, 0, stream>>>((const _Float16*)m16, (const _Float16*)xh,
                                             BT, bias, out);
}